// Round 7
// baseline (581.241 us; speedup 1.0000x reference)
//
#include <hip/hip_runtime.h>

#define NB  4
#define CCH 256
#define NN  4096
#define KD  32
#define OD  256

typedef __attribute__((ext_vector_type(8))) __bf16 bf16x8;
typedef __attribute__((ext_vector_type(4))) float  floatx4;

__device__ __forceinline__ unsigned short f2bf(float f) {
    union { float f; unsigned u; } v; v.f = f;
    unsigned r = v.u + 0x7FFFu + ((v.u >> 16) & 1u);
    return (unsigned short)(r >> 16);
}
__device__ __forceinline__ float bf2f(unsigned short h) {
    union { unsigned u; float f; } v; v.u = ((unsigned)h) << 16;
    return v.f;
}
// 16B fragment from 4B-aligned LDS (rows are 132B -> b128 would misalign)
__device__ __forceinline__ bf16x8 ldfrag(const unsigned short* p) {
    union { bf16x8 v; unsigned u[4]; } r;
    r.u[0] = *(const unsigned*)(p + 0);
    r.u[1] = *(const unsigned*)(p + 2);
    r.u[2] = *(const unsigned*)(p + 4);
    r.u[3] = *(const unsigned*)(p + 6);
    return r.v;
}

// ---------------------------------------------------------------------------
// Projection as split-bf16 MFMA GEMM (byte-identical math to rounds 3-6).
// Round-6 probe measured this kernel's warm intrinsic cost: ~30 µs.
// Single launch restored this round.
// ---------------------------------------------------------------------------
#define WPAD 66    // W/Xt row stride in ushorts (132 B, 33 dwords: bank-spread)
#define VPAD 136   // Vt row stride (272 B, 16B-aligned for b128 epilogue reads)

__global__ __launch_bounds__(256) void proj_kernel(
    const float* __restrict__ x,
    const float* __restrict__ Wq, const float* __restrict__ bq,
    const float* __restrict__ Wk, const float* __restrict__ bk,
    const float* __restrict__ Wv, const float* __restrict__ bv,
    unsigned short* __restrict__ Qb, unsigned short* __restrict__ Ktb,
    unsigned short* __restrict__ Vb)
{
    __shared__ __align__(16) unsigned char smem[50944];
    unsigned short* Wh   = (unsigned short*)smem;            // [64][66] 8448 B
    unsigned short* Wl   = (unsigned short*)(smem + 8448);   // [64][66]
    unsigned short* Xth  = (unsigned short*)(smem + 16896);  // [128][66] 16896 B
    unsigned short* Xtl  = (unsigned short*)(smem + 33792);  // [128][66]
    float*          bias = (float*)(smem + 50688);           // [64]
    unsigned short* Yt = (unsigned short*)(smem + 16896);    // mc==0: [128][66]
    unsigned short* Vt = (unsigned short*)(smem + 16896);    // mc>=1: [64][136]

    // XCD panel-affinity decode (round 5)
    const int bid = blockIdx.x;            // 0..639
    const int mc  = bid >> 7;              // 0..4 : 64-row o-chunk
    const int pnl = bid & 127;             // panel id: all 5 mc's share XCD pnl%8
    const int nb  = pnl & 31;              // 0..31: 128-px tile
    const int b   = pnl >> 5;              // 0..3

    const int tid = threadIdx.x;
    const int wave = tid >> 6;
    const int lane = tid & 63;
    const int quad = lane >> 4;
    const int li   = lane & 15;
    const int pxw  = wave * 32;            // wave's 32-px sub-tile
    const int px0  = nb * 128;

    const float* xb = x + (size_t)b * CCH * NN;

    floatx4 acc[4][2];
    #pragma unroll
    for (int mf = 0; mf < 4; ++mf)
        #pragma unroll
        for (int nf = 0; nf < 2; ++nf)
            acc[mf][nf] = (floatx4){0.f, 0.f, 0.f, 0.f};

    for (int ks = 0; ks < 4; ++ks) {
        const int c0 = ks * 64;
        __syncthreads();   // prior-slice fragment reads complete

        // ---- stage W slice [64 rows][64 c] -> Wh/Wl (hi/lo bf16) ----
        #pragma unroll
        for (int i = 0; i < 4; ++i) {
            int idx4 = i * 256 + tid;          // 0..1023
            int row  = idx4 >> 4;              // 0..63
            int c4   = (idx4 & 15) * 4;        // 0..60
            const float* src;
            if (mc == 0) src = (row < 32) ? (Wq + row * CCH) : (Wk + (row - 32) * CCH);
            else         src = Wv + ((size_t)((mc - 1) * 64 + row)) * CCH;
            floatx4 w = *(const floatx4*)(src + c0 + c4);
            #pragma unroll
            for (int j = 0; j < 4; ++j) {
                unsigned short h = f2bf(w[j]);
                unsigned short l = f2bf(w[j] - bf2f(h));
                Wh[row * WPAD + c4 + j] = h;
                Wl[row * WPAD + c4 + j] = l;
            }
        }
        // ---- stage x slice [64 c][128 px] transposed -> Xth/Xtl[px][c] ----
        #pragma unroll
        for (int i = 0; i < 8; ++i) {
            int idx4 = i * 256 + tid;          // 0..2047
            int c    = idx4 >> 5;              // 0..63
            int px   = (idx4 & 31) * 4;        // 0..124
            floatx4 v = *(const floatx4*)(xb + (size_t)(c0 + c) * NN + px0 + px);
            #pragma unroll
            for (int j = 0; j < 4; ++j) {
                unsigned short h = f2bf(v[j]);
                unsigned short l = f2bf(v[j] - bf2f(h));
                Xth[(px + j) * WPAD + c] = h;
                Xtl[(px + j) * WPAD + c] = l;
            }
        }
        if (ks == 0 && tid < 64) {
            float bb;
            if (mc == 0) bb = (tid < 32) ? bq[tid] : bk[tid - 32];
            else         bb = bv[(mc - 1) * 64 + tid];
            bias[tid] = bb;
        }
        __syncthreads();   // slice staged

        // ---- MFMA: 2 k-steps of 32, 4m x 2n frags, 3 split terms ----
        #pragma unroll
        for (int kk = 0; kk < 2; ++kk) {
            bf16x8 ah[4], al[4], bh[2], bl[2];
            #pragma unroll
            for (int mf = 0; mf < 4; ++mf) {
                const int ro = (mf * 16 + li) * WPAD + kk * 32 + quad * 8;
                ah[mf] = ldfrag(Wh + ro);
                al[mf] = ldfrag(Wl + ro);
            }
            #pragma unroll
            for (int nf = 0; nf < 2; ++nf) {
                const int ro = (pxw + nf * 16 + li) * WPAD + kk * 32 + quad * 8;
                bh[nf] = ldfrag(Xth + ro);
                bl[nf] = ldfrag(Xtl + ro);
            }
            #pragma unroll
            for (int mf = 0; mf < 4; ++mf)
                #pragma unroll
                for (int nf = 0; nf < 2; ++nf) {
                    acc[mf][nf] = __builtin_amdgcn_mfma_f32_16x16x32_bf16(ah[mf], bh[nf], acc[mf][nf], 0, 0, 0);
                    acc[mf][nf] = __builtin_amdgcn_mfma_f32_16x16x32_bf16(ah[mf], bl[nf], acc[mf][nf], 0, 0, 0);
                    acc[mf][nf] = __builtin_amdgcn_mfma_f32_16x16x32_bf16(al[mf], bh[nf], acc[mf][nf], 0, 0, 0);
                }
        }
    }

    // ---- epilogue: + bias, bounce through LDS, streaming stores ----
    __syncthreads();   // all fragment reads done; reuse Xt region
    if (mc == 0) {
        // Yt[px][o] : Q cols 0-31, K cols 32-63
        #pragma unroll
        for (int mf = 0; mf < 4; ++mf)
            #pragma unroll
            for (int nf = 0; nf < 2; ++nf)
                #pragma unroll
                for (int r = 0; r < 4; ++r) {
                    const int o = mf * 16 + quad * 4 + r;
                    float f = acc[mf][nf][r] + bias[o];
                    Yt[(pxw + nf * 16 + li) * WPAD + o] = f2bf(f);
                }
        __syncthreads();
        if (tid < 128) {
            const int px = tid;
            const size_t n = (size_t)(b * NN + px0 + px);
            unsigned short* qdst = Qb  + n * KD;
            unsigned short* kdst = Ktb + n * KD;
            const unsigned short* src = Yt + px * WPAD;
            #pragma unroll
            for (int i = 0; i < 4; ++i) {   // 4 x 16B per 64B row
                union { uint4 u4; unsigned u[4]; } q, k;
                #pragma unroll
                for (int j = 0; j < 4; ++j) {
                    q.u[j] = *(const unsigned*)(src + i * 8 + j * 2);
                    k.u[j] = *(const unsigned*)(src + 32 + i * 8 + j * 2);
                }
                *(uint4*)(qdst + i * 8) = q.u4;
                *(uint4*)(kdst + i * 8) = k.u4;
            }
        }
    } else {
        // Vt[o][px]
        #pragma unroll
        for (int mf = 0; mf < 4; ++mf)
            #pragma unroll
            for (int nf = 0; nf < 2; ++nf)
                #pragma unroll
                for (int r = 0; r < 4; ++r) {
                    const int o = mf * 16 + quad * 4 + r;
                    float f = acc[mf][nf][r] + bias[o];
                    Vt[o * VPAD + pxw + nf * 16 + li] = f2bf(f);
                }
        __syncthreads();
        const int ol   = tid >> 2;          // 0..63
        const int part = tid & 3;           // 32-px quarter
        const unsigned short* src = Vt + ol * VPAD + part * 32;
        unsigned short* dst = Vb + (size_t)(b * OD + (mc - 1) * 64 + ol) * NN + px0 + part * 32;
        *(uint4*)(dst + 0) = *(const uint4*)(src + 0);
        *(uint4*)(dst + 8) = *(const uint4*)(src + 8);
        *(uint4*)(dst + 16) = *(const uint4*)(src + 16);
        *(uint4*)(dst + 24) = *(const uint4*)(src + 24);
    }
}

// ---------------------------------------------------------------------------
// Fused attention (byte-identical to round 5).
// ROUND 7 PROBE: launched TWICE.  attn is idempotent (reads x, gamma, Qb,
// Ktb, Vb; pure-overwrites out & attn; never reads its outputs), so the
// second, cache-warm launch's marginal cost = attn's intrinsic duration.
// This resolves the attn-vs-tax split of the remaining ~220 µs budget.
// ---------------------------------------------------------------------------
__global__ __launch_bounds__(256, 2) void attn_kernel(
    const float* __restrict__ x, const float* __restrict__ gammap,
    const unsigned short* __restrict__ Qb,
    const unsigned short* __restrict__ Ktb,
    const unsigned short* __restrict__ Vb,
    float* __restrict__ out, float* __restrict__ attn)
{
    __shared__ __align__(16) unsigned char smem[63744];
    unsigned short* Vlds  = (unsigned short*)smem;           // 2 x [256][40] bf16 = 40960 B
    float*          panel = (float*)(smem + 40960);          // 4 x [16][68] f32  = 17408 B
    unsigned short* Pl    = (unsigned short*)(smem + 58368); // 4 x [16][40] bf16 =  5120 B
    float*          sred  = (float*)(smem + 63488);          // [2][2][16] f32    =   256 B

    const int tid  = threadIdx.x;
    const int wave = tid >> 6;
    const int lane = tid & 63;
    const int quad = lane >> 4;
    const int li   = lane & 15;
    const int g    = wave & 1;    // row group (16 rows)
    const int h    = wave >> 1;   // n-half

    // XCD batch-affinity decode (round 5)
    const int bid = blockIdx.x;               // 0..511
    const int b   = (bid & 7) >> 1;           // batch -> XCD pair {2b, 2b+1}
    const int mt  = ((bid >> 3) << 1) | (bid & 1);   // 0..127 m-tile
    const int mw  = mt * 32;                  // block's 32 query rows
    const int hb  = h * 2048;                 // wave's n-range start

    unsigned short* Vh   = Vlds + h * 10240;       // this wave's V chunk (shorts)
    float*          pan  = panel + wave * 1088;    // [16][68] f32
    unsigned short* Plds = Pl + wave * 640;        // [16][40] bf16

    const floatx4 zero = {0.f, 0.f, 0.f, 0.f};

    // A-frag (Q rows), loaded once: A[m=li][k=quad*8+j]
    const bf16x8 aQ = *(const bf16x8*)(Qb + (size_t)(b * NN + mw + g * 16 + li) * KD + quad * 8);
    const unsigned short* ktbase = Ktb + (size_t)b * NN * KD + quad * 8;

    // ---- sweep 1: partial softmax denominator over this wave's n-half ----
    float lrow[4] = {0.f, 0.f, 0.f, 0.f};
    #pragma unroll 4
    for (int nt = 0; nt < 128; ++nt) {
        bf16x8 bK = *(const bf16x8*)(ktbase + (size_t)(hb + nt * 16 + li) * KD);
        floatx4 s = __builtin_amdgcn_mfma_f32_16x16x32_bf16(aQ, bK, zero, 0, 0, 0);
        #pragma unroll
        for (int r = 0; r < 4; ++r) lrow[r] += __expf(s[r]);
    }
    #pragma unroll
    for (int r = 0; r < 4; ++r) {
        #pragma unroll
        for (int xm = 1; xm < 16; xm <<= 1)
            lrow[r] += __shfl_xor(lrow[r], xm);
    }
    if (li == 0) {
        #pragma unroll
        for (int r = 0; r < 4; ++r) sred[(g * 2 + h) * 16 + quad * 4 + r] = lrow[r];
    }
    __syncthreads();          // no stores outstanding yet: cheap drain
    float linv[4];
    #pragma unroll
    for (int r = 0; r < 4; ++r) {
        const int row = quad * 4 + r;
        linv[r] = 1.0f / (sred[(g * 2 + 0) * 16 + row] + sred[(g * 2 + 1) * 16 + row]);
    }

    // ---- sweep 2: attention panels + PV, 64 chunks of 32 n ----
    floatx4 oacc[16];
    #pragma unroll
    for (int ot = 0; ot < 16; ++ot) oacc[ot] = zero;

    // staging role: waves 0,1 stage half 0; waves 2,3 stage half 1
    const int hs = tid >> 7;
    const int st = tid & 127;
    const unsigned short* vsrc = Vb + (size_t)b * OD * NN + hs * 2048;
    unsigned short*       vdst = Vlds + hs * 10240;

    // prefetch V chunk 0 into regs
    bf16x8 vtmp[8];
    #pragma unroll
    for (int i = 0; i < 8; ++i) {
        int linear = i * 128 + st;
        int o = linear >> 2, p = linear & 3;
        vtmp[i] = *(const bf16x8*)(vsrc + (size_t)o * NN + p * 8);
    }

    for (int c = 0; c < 64; ++c) {
        const int n0 = hb + c * 32;

        // barrier 1: all waves' PV reads of the previous V chunk have retired
        __builtin_amdgcn_s_barrier();

        // write V[c] to LDS (counted vmcnt drains only vtmp loads; flush
        // stores were issued later and stay in flight)
        #pragma unroll
        for (int i = 0; i < 8; ++i) {
            int linear = i * 128 + st;
            int o = linear >> 2, p = linear & 3;
            *(bf16x8*)(vdst + o * 40 + p * 8) = vtmp[i];
        }
        asm volatile("s_waitcnt lgkmcnt(0)" ::: "memory");
        __builtin_amdgcn_s_barrier();   // barrier 2: V chunk visible to all

        // K loads for this chunk
        bf16x8 bK0 = *(const bf16x8*)(ktbase + (size_t)(n0 + li) * KD);
        bf16x8 bK1 = *(const bf16x8*)(ktbase + (size_t)(n0 + 16 + li) * KD);

        // V prefetch for next chunk
        if (c < 63) {
            #pragma unroll
            for (int i = 0; i < 8; ++i) {
                int linear = i * 128 + st;
                int o = linear >> 2, p = linear & 3;
                vtmp[i] = *(const bf16x8*)(vsrc + (size_t)o * NN + (c + 1) * 32 + p * 8);
            }
        }

        floatx4 s0 = __builtin_amdgcn_mfma_f32_16x16x32_bf16(aQ, bK0, zero, 0, 0, 0);
        floatx4 s1 = __builtin_amdgcn_mfma_f32_16x16x32_bf16(aQ, bK1, zero, 0, 0, 0);
        const int cc = c & 1;
        #pragma unroll
        for (int r = 0; r < 4; ++r) {
            float p0 = __expf(s0[r]) * linv[r];
            float p1 = __expf(s1[r]) * linv[r];
            const int row = quad * 4 + r;
            pan[row * 68 + cc * 32 + li]      = p0;     // fp32 panel (for streaming store)
            pan[row * 68 + cc * 32 + 16 + li] = p1;
            Plds[row * 40 + li]      = f2bf(p0);        // bf16 P (for PV A-frag)
            Plds[row * 40 + 16 + li] = f2bf(p1);
        }
        // A-frag of P (wave-internal LDS round-trip)
        bf16x8 aP = *(const bf16x8*)(Plds + li * 40 + quad * 8);
        #pragma unroll
        for (int ot = 0; ot < 16; ++ot) {
            bf16x8 bV = *(const bf16x8*)(Vh + (ot * 16 + li) * 40 + quad * 8);
            oacc[ot] = __builtin_amdgcn_mfma_f32_16x16x32_bf16(aP, bV, oacc[ot], 0, 0, 0);
        }
        if (cc) {
            // flush panel LAST: stores never waited on inside the loop
            float* ab = attn + ((size_t)(b * NN + mw + g * 16)) * NN + hb + (c - 1) * 32;
            #pragma unroll
            for (int it = 0; it < 4; ++it) {
                int row = it * 4 + quad;
                floatx4 v = *(const floatx4*)(pan + row * 68 + li * 4);
                *(floatx4*)(ab + (size_t)row * NN + li * 4) = v;
            }
        }
    }

    // ---- epilogue: cross-wave (n-half) O reduce, then out = gamma*O + x ----
    __syncthreads();   // single full drain of the store stream (end of loop)
    float* Olds = (float*)(void*)smem;   // [256][36] f32, reuses V region
    if (h == 0) {
        #pragma unroll
        for (int ot = 0; ot < 16; ++ot)
            #pragma unroll
            for (int r = 0; r < 4; ++r)
                Olds[(ot * 16 + li) * 36 + g * 16 + quad * 4 + r] = oacc[ot][r];
    }
    __syncthreads();
    if (h == 1) {
        #pragma unroll
        for (int ot = 0; ot < 16; ++ot)
            #pragma unroll
            for (int r = 0; r < 4; ++r)
                Olds[(ot * 16 + li) * 36 + g * 16 + quad * 4 + r] += oacc[ot][r];
    }
    __syncthreads();
    const float gm = gammap[0];
    #pragma unroll
    for (int it = 0; it < 8; ++it) {
        int linear = it * 256 + tid;
        int o = linear >> 3, seg = linear & 7;
        floatx4 ov = *(const floatx4*)(Olds + o * 36 + seg * 4);
        size_t gidx = (size_t)(b * OD + o) * NN + mw + seg * 4;
        floatx4 xv = *(const floatx4*)(x + gidx);
        floatx4 res;
        res[0] = gm * ov[0] + xv[0];
        res[1] = gm * ov[1] + xv[1];
        res[2] = gm * ov[2] + xv[2];
        res[3] = gm * ov[3] + xv[3];
        *(floatx4*)(out + gidx) = res;
    }
}

extern "C" void kernel_launch(void* const* d_in, const int* in_sizes, int n_in,
                              void* d_out, int out_size, void* d_ws, size_t ws_size,
                              hipStream_t stream) {
    const float* x     = (const float*)d_in[0];
    const float* Wq    = (const float*)d_in[1];
    const float* bq    = (const float*)d_in[2];
    const float* Wk    = (const float*)d_in[3];
    const float* bk    = (const float*)d_in[4];
    const float* Wv    = (const float*)d_in[5];
    const float* bv    = (const float*)d_in[6];
    const float* gamma = (const float*)d_in[7];

    float* out  = (float*)d_out;
    float* attn = out + (size_t)NB * OD * NN;          // outputs concatenated: out then attention

    unsigned short* Qb  = (unsigned short*)d_ws;       // B*N*32 bf16 = 1 MB
    unsigned short* Ktb = Qb  + (size_t)NB * NN * KD;  // 1 MB
    unsigned short* Vb  = Ktb + (size_t)NB * NN * KD;  // B*O*N bf16 = 8 MB

    proj_kernel<<<dim3(640), 256, 0, stream>>>(x, Wq, bq, Wk, bk, Wv, bv, Qb, Ktb, Vb);
    // ROUND 7 PROBE: attn launched twice (idempotent).  Marginal cost of the
    // second, cache-warm launch = attn's intrinsic duration.
    attn_kernel<<<dim3(512), 256, 0, stream>>>(x, gamma, Qb, Ktb, Vb, out, attn);
    attn_kernel<<<dim3(512), 256, 0, stream>>>(x, gamma, Qb, Ktb, Vb, out, attn);
}

// Round 8
// 435.063 us; speedup vs baseline: 1.3360x; 1.3360x over previous
//
#include <hip/hip_runtime.h>

#define NB  4
#define CCH 256
#define NN  4096
#define KD  32
#define OD  256

typedef __attribute__((ext_vector_type(8))) __bf16 bf16x8;
typedef __attribute__((ext_vector_type(4))) float  floatx4;

__device__ __forceinline__ unsigned short f2bf(float f) {
    union { float f; unsigned u; } v; v.f = f;
    unsigned r = v.u + 0x7FFFu + ((v.u >> 16) & 1u);
    return (unsigned short)(r >> 16);
}
__device__ __forceinline__ float bf2f(unsigned short h) {
    union { unsigned u; float f; } v; v.u = ((unsigned)h) << 16;
    return v.f;
}
// 16B fragment from 4B-aligned LDS (rows are 132B -> b128 would misalign)
__device__ __forceinline__ bf16x8 ldfrag(const unsigned short* p) {
    union { bf16x8 v; unsigned u[4]; } r;
    r.u[0] = *(const unsigned*)(p + 0);
    r.u[1] = *(const unsigned*)(p + 2);
    r.u[2] = *(const unsigned*)(p + 4);
    r.u[3] = *(const unsigned*)(p + 6);
    return r.v;
}

// ---------------------------------------------------------------------------
// Projection as split-bf16 MFMA GEMM (byte-identical to round 5; warm ~30 µs).
// ---------------------------------------------------------------------------
#define WPAD 66    // W/Xt row stride in ushorts (132 B, 33 dwords: bank-spread)
#define VPAD 136   // Vt row stride (272 B, 16B-aligned for b128 epilogue reads)

__global__ __launch_bounds__(256) void proj_kernel(
    const float* __restrict__ x,
    const float* __restrict__ Wq, const float* __restrict__ bq,
    const float* __restrict__ Wk, const float* __restrict__ bk,
    const float* __restrict__ Wv, const float* __restrict__ bv,
    unsigned short* __restrict__ Qb, unsigned short* __restrict__ Ktb,
    unsigned short* __restrict__ Vb)
{
    __shared__ __align__(16) unsigned char smem[50944];
    unsigned short* Wh   = (unsigned short*)smem;            // [64][66] 8448 B
    unsigned short* Wl   = (unsigned short*)(smem + 8448);   // [64][66]
    unsigned short* Xth  = (unsigned short*)(smem + 16896);  // [128][66] 16896 B
    unsigned short* Xtl  = (unsigned short*)(smem + 33792);  // [128][66]
    float*          bias = (float*)(smem + 50688);           // [64]
    unsigned short* Yt = (unsigned short*)(smem + 16896);    // mc==0: [128][66]
    unsigned short* Vt = (unsigned short*)(smem + 16896);    // mc>=1: [64][136]

    // XCD panel-affinity decode (round 5)
    const int bid = blockIdx.x;            // 0..639
    const int mc  = bid >> 7;              // 0..4 : 64-row o-chunk
    const int pnl = bid & 127;             // panel id: all 5 mc's share XCD pnl%8
    const int nb  = pnl & 31;              // 0..31: 128-px tile
    const int b   = pnl >> 5;              // 0..3

    const int tid = threadIdx.x;
    const int wave = tid >> 6;
    const int lane = tid & 63;
    const int quad = lane >> 4;
    const int li   = lane & 15;
    const int pxw  = wave * 32;            // wave's 32-px sub-tile
    const int px0  = nb * 128;

    const float* xb = x + (size_t)b * CCH * NN;

    floatx4 acc[4][2];
    #pragma unroll
    for (int mf = 0; mf < 4; ++mf)
        #pragma unroll
        for (int nf = 0; nf < 2; ++nf)
            acc[mf][nf] = (floatx4){0.f, 0.f, 0.f, 0.f};

    for (int ks = 0; ks < 4; ++ks) {
        const int c0 = ks * 64;
        __syncthreads();   // prior-slice fragment reads complete

        // ---- stage W slice [64 rows][64 c] -> Wh/Wl (hi/lo bf16) ----
        #pragma unroll
        for (int i = 0; i < 4; ++i) {
            int idx4 = i * 256 + tid;          // 0..1023
            int row  = idx4 >> 4;              // 0..63
            int c4   = (idx4 & 15) * 4;        // 0..60
            const float* src;
            if (mc == 0) src = (row < 32) ? (Wq + row * CCH) : (Wk + (row - 32) * CCH);
            else         src = Wv + ((size_t)((mc - 1) * 64 + row)) * CCH;
            floatx4 w = *(const floatx4*)(src + c0 + c4);
            #pragma unroll
            for (int j = 0; j < 4; ++j) {
                unsigned short h = f2bf(w[j]);
                unsigned short l = f2bf(w[j] - bf2f(h));
                Wh[row * WPAD + c4 + j] = h;
                Wl[row * WPAD + c4 + j] = l;
            }
        }
        // ---- stage x slice [64 c][128 px] transposed -> Xth/Xtl[px][c] ----
        #pragma unroll
        for (int i = 0; i < 8; ++i) {
            int idx4 = i * 256 + tid;          // 0..2047
            int c    = idx4 >> 5;              // 0..63
            int px   = (idx4 & 31) * 4;        // 0..124
            floatx4 v = *(const floatx4*)(xb + (size_t)(c0 + c) * NN + px0 + px);
            #pragma unroll
            for (int j = 0; j < 4; ++j) {
                unsigned short h = f2bf(v[j]);
                unsigned short l = f2bf(v[j] - bf2f(h));
                Xth[(px + j) * WPAD + c] = h;
                Xtl[(px + j) * WPAD + c] = l;
            }
        }
        if (ks == 0 && tid < 64) {
            float bb;
            if (mc == 0) bb = (tid < 32) ? bq[tid] : bk[tid - 32];
            else         bb = bv[(mc - 1) * 64 + tid];
            bias[tid] = bb;
        }
        __syncthreads();   // slice staged

        // ---- MFMA: 2 k-steps of 32, 4m x 2n frags, 3 split terms ----
        #pragma unroll
        for (int kk = 0; kk < 2; ++kk) {
            bf16x8 ah[4], al[4], bh[2], bl[2];
            #pragma unroll
            for (int mf = 0; mf < 4; ++mf) {
                const int ro = (mf * 16 + li) * WPAD + kk * 32 + quad * 8;
                ah[mf] = ldfrag(Wh + ro);
                al[mf] = ldfrag(Wl + ro);
            }
            #pragma unroll
            for (int nf = 0; nf < 2; ++nf) {
                const int ro = (pxw + nf * 16 + li) * WPAD + kk * 32 + quad * 8;
                bh[nf] = ldfrag(Xth + ro);
                bl[nf] = ldfrag(Xtl + ro);
            }
            #pragma unroll
            for (int mf = 0; mf < 4; ++mf)
                #pragma unroll
                for (int nf = 0; nf < 2; ++nf) {
                    acc[mf][nf] = __builtin_amdgcn_mfma_f32_16x16x32_bf16(ah[mf], bh[nf], acc[mf][nf], 0, 0, 0);
                    acc[mf][nf] = __builtin_amdgcn_mfma_f32_16x16x32_bf16(ah[mf], bl[nf], acc[mf][nf], 0, 0, 0);
                    acc[mf][nf] = __builtin_amdgcn_mfma_f32_16x16x32_bf16(al[mf], bh[nf], acc[mf][nf], 0, 0, 0);
                }
        }
    }

    // ---- epilogue: + bias, bounce through LDS, streaming stores ----
    __syncthreads();   // all fragment reads done; reuse Xt region
    if (mc == 0) {
        // Yt[px][o] : Q cols 0-31, K cols 32-63
        #pragma unroll
        for (int mf = 0; mf < 4; ++mf)
            #pragma unroll
            for (int nf = 0; nf < 2; ++nf)
                #pragma unroll
                for (int r = 0; r < 4; ++r) {
                    const int o = mf * 16 + quad * 4 + r;
                    float f = acc[mf][nf][r] + bias[o];
                    Yt[(pxw + nf * 16 + li) * WPAD + o] = f2bf(f);
                }
        __syncthreads();
        if (tid < 128) {
            const int px = tid;
            const size_t n = (size_t)(b * NN + px0 + px);
            unsigned short* qdst = Qb  + n * KD;
            unsigned short* kdst = Ktb + n * KD;
            const unsigned short* src = Yt + px * WPAD;
            #pragma unroll
            for (int i = 0; i < 4; ++i) {   // 4 x 16B per 64B row
                union { uint4 u4; unsigned u[4]; } q, k;
                #pragma unroll
                for (int j = 0; j < 4; ++j) {
                    q.u[j] = *(const unsigned*)(src + i * 8 + j * 2);
                    k.u[j] = *(const unsigned*)(src + 32 + i * 8 + j * 2);
                }
                *(uint4*)(qdst + i * 8) = q.u4;
                *(uint4*)(kdst + i * 8) = k.u4;
            }
        }
    } else {
        // Vt[o][px]
        #pragma unroll
        for (int mf = 0; mf < 4; ++mf)
            #pragma unroll
            for (int nf = 0; nf < 2; ++nf)
                #pragma unroll
                for (int r = 0; r < 4; ++r) {
                    const int o = mf * 16 + quad * 4 + r;
                    float f = acc[mf][nf][r] + bias[o];
                    Vt[o * VPAD + pxw + nf * 16 + li] = f2bf(f);
                }
        __syncthreads();
        const int ol   = tid >> 2;          // 0..63
        const int part = tid & 3;           // 32-px quarter
        const unsigned short* src = Vt + ol * VPAD + part * 32;
        unsigned short* dst = Vb + (size_t)(b * OD + (mc - 1) * 64 + ol) * NN + px0 + part * 32;
        *(uint4*)(dst + 0) = *(const uint4*)(src + 0);
        *(uint4*)(dst + 8) = *(const uint4*)(src + 8);
        *(uint4*)(dst + 16) = *(const uint4*)(src + 16);
        *(uint4*)(dst + 24) = *(const uint4*)(src + 24);
    }
}

// ---------------------------------------------------------------------------
// Fused attention, 64-row m-tile version (round 8):
//   256 blocks x 512 threads (8 waves = 4 row-groups g x 2 n-halves h).
//   Same occupancy as r5 (2 waves/SIMD) but HALF the blocks -> V L2 traffic
//   1 GB -> 512 MB, K 256 -> 128 MB (each staged V chunk now feeds 4 waves
//   per half instead of 2).
//   + K register prefetch one chunk ahead (kills per-chunk exposed L2 lat).
//   + P LDS round-trip removed: aP rebuilt from the fp32 panel (bit-identical
//     f2bf), deleting 8 scalar ds_writes + stride-40 read per chunk per wave.
//   Store discipline unchanged: flush stores issued last, counted vmcnt only,
//   raw s_barrier in the main loop, single drain at the end.
// ---------------------------------------------------------------------------
__global__ __launch_bounds__(512, 2) void attn_kernel(
    const float* __restrict__ x, const float* __restrict__ gammap,
    const unsigned short* __restrict__ Qb,
    const unsigned short* __restrict__ Ktb,
    const unsigned short* __restrict__ Vb,
    float* __restrict__ out, float* __restrict__ attn)
{
    __shared__ __align__(16) unsigned char smem[59904];
    unsigned short* Vlds  = (unsigned short*)smem;           // 2 x [256][40] bf16 = 40960 B
    float*          panel = (float*)(smem + 40960);          // 8 x [16][36] f32  = 18432 B
    float*          sred  = (float*)(smem + 59392);          // [4][2][16] f32    =   512 B

    const int tid  = threadIdx.x;
    const int wave = tid >> 6;        // 0..7
    const int lane = tid & 63;
    const int quad = lane >> 4;
    const int li   = lane & 15;
    const int g    = wave & 3;        // row group of 16 (0..3)
    const int h    = wave >> 2;       // n-half

    // XCD batch-affinity decode (256 blocks: batch b -> XCD pair {2b,2b+1})
    const int bid = blockIdx.x;               // 0..255
    const int b   = (bid & 7) >> 1;
    const int mt  = ((bid >> 3) << 1) | (bid & 1);   // 0..63 m-tile
    const int mw  = mt * 64;                  // block's 64 query rows
    const int hb  = h * 2048;                 // wave's n-range start

    unsigned short* Vh  = Vlds + h * 10240;   // this wave's V half-chunk
    float*          pan = panel + wave * 576; // [16][36] f32

    const floatx4 zero = {0.f, 0.f, 0.f, 0.f};

    // A-frag (Q rows), loaded once: A[m=li][k=quad*8+j]
    const bf16x8 aQ = *(const bf16x8*)(Qb + (size_t)(b * NN + mw + g * 16 + li) * KD + quad * 8);
    const unsigned short* ktbase = Ktb + (size_t)b * NN * KD + quad * 8;

    // ---- sweep 1: partial softmax denominator over this wave's n-half ----
    float lrow[4] = {0.f, 0.f, 0.f, 0.f};
    #pragma unroll 4
    for (int nt = 0; nt < 128; ++nt) {
        bf16x8 bK = *(const bf16x8*)(ktbase + (size_t)(hb + nt * 16 + li) * KD);
        floatx4 s = __builtin_amdgcn_mfma_f32_16x16x32_bf16(aQ, bK, zero, 0, 0, 0);
        #pragma unroll
        for (int r = 0; r < 4; ++r) lrow[r] += __expf(s[r]);
    }
    #pragma unroll
    for (int r = 0; r < 4; ++r) {
        #pragma unroll
        for (int xm = 1; xm < 16; xm <<= 1)
            lrow[r] += __shfl_xor(lrow[r], xm);
    }
    if (li == 0) {
        #pragma unroll
        for (int r = 0; r < 4; ++r) sred[(g * 2 + h) * 16 + quad * 4 + r] = lrow[r];
    }
    __syncthreads();          // no stores outstanding yet: cheap drain
    float linv[4];
    #pragma unroll
    for (int r = 0; r < 4; ++r) {
        const int row = quad * 4 + r;
        linv[r] = 1.0f / (sred[(g * 2 + 0) * 16 + row] + sred[(g * 2 + 1) * 16 + row]);
    }

    // ---- sweep 2: attention panels + PV, 64 chunks of 32 n ----
    floatx4 oacc[16];
    #pragma unroll
    for (int ot = 0; ot < 16; ++ot) oacc[ot] = zero;

    // staging role: threads 0-255 stage half 0; 256-511 stage half 1
    const int hs = tid >> 8;
    const int st = tid & 255;
    const unsigned short* vsrc = Vb + (size_t)b * OD * NN + hs * 2048;
    unsigned short*       vdst = Vlds + hs * 10240;

    // prefetch V chunk 0 into regs, then K chunk 0
    bf16x8 vtmp[4];
    #pragma unroll
    for (int i = 0; i < 4; ++i) {
        int linear = i * 256 + st;
        int o = linear >> 2, p = linear & 3;
        vtmp[i] = *(const bf16x8*)(vsrc + (size_t)o * NN + p * 8);
    }
    bf16x8 bK0 = *(const bf16x8*)(ktbase + (size_t)(hb + li) * KD);
    bf16x8 bK1 = *(const bf16x8*)(ktbase + (size_t)(hb + 16 + li) * KD);

    for (int c = 0; c < 64; ++c) {
        // barrier 1: all waves' PV reads of the previous V chunk have retired
        __builtin_amdgcn_s_barrier();

        // write V[c] to LDS (counted vmcnt drains only the V/K loads; flush
        // stores were issued after them and stay in flight)
        #pragma unroll
        for (int i = 0; i < 4; ++i) {
            int linear = i * 256 + st;
            int o = linear >> 2, p = linear & 3;
            *(bf16x8*)(vdst + o * 40 + p * 8) = vtmp[i];
        }
        asm volatile("s_waitcnt lgkmcnt(0)" ::: "memory");
        __builtin_amdgcn_s_barrier();   // barrier 2: V chunk visible to all

        // QK^T immediately from registers (K was prefetched last iteration)
        floatx4 s0 = __builtin_amdgcn_mfma_f32_16x16x32_bf16(aQ, bK0, zero, 0, 0, 0);
        floatx4 s1 = __builtin_amdgcn_mfma_f32_16x16x32_bf16(aQ, bK1, zero, 0, 0, 0);

        // prefetch K and V for chunk c+1 (latency hides under exp+PV+flush)
        bf16x8 nK0, nK1;
        if (c < 63) {
            const int n1 = hb + (c + 1) * 32;
            nK0 = *(const bf16x8*)(ktbase + (size_t)(n1 + li) * KD);
            nK1 = *(const bf16x8*)(ktbase + (size_t)(n1 + 16 + li) * KD);
            #pragma unroll
            for (int i = 0; i < 4; ++i) {
                int linear = i * 256 + st;
                int o = linear >> 2, p = linear & 3;
                vtmp[i] = *(const bf16x8*)(vsrc + (size_t)o * NN + (c + 1) * 32 + p * 8);
            }
        }

        #pragma unroll
        for (int r = 0; r < 4; ++r) {
            float p0 = __expf(s0[r]) * linv[r];
            float p1 = __expf(s1[r]) * linv[r];
            const int row = quad * 4 + r;
            pan[row * 36 + li]      = p0;     // fp32 panel (store + aP source)
            pan[row * 36 + 16 + li] = p1;
        }
        // A-frag of P rebuilt from panel (wave-internal, lgkm-ordered)
        {
            const float* prow = pan + li * 36 + quad * 8;
            floatx4 pa = *(const floatx4*)(prow);
            floatx4 pb = *(const floatx4*)(prow + 4);
            union { bf16x8 v; unsigned short s[8]; } ap;
            #pragma unroll
            for (int j = 0; j < 4; ++j) {
                ap.s[j]     = f2bf(pa[j]);
                ap.s[4 + j] = f2bf(pb[j]);
            }
            #pragma unroll
            for (int ot = 0; ot < 16; ++ot) {
                bf16x8 bV = *(const bf16x8*)(Vh + (ot * 16 + li) * 40 + quad * 8);
                oacc[ot] = __builtin_amdgcn_mfma_f32_16x16x32_bf16(ap.v, bV, oacc[ot], 0, 0, 0);
            }
        }
        // flush panel LAST: 128B-contiguous runs, stores never waited on
        {
            float* ab = attn + ((size_t)(b * NN + mw + g * 16)) * NN + hb + c * 32;
            #pragma unroll
            for (int it = 0; it < 2; ++it) {
                int row = it * 8 + (lane >> 3);
                int c4  = (lane & 7) * 4;
                floatx4 v = *(const floatx4*)(pan + row * 36 + c4);
                *(floatx4*)(ab + (size_t)row * NN + c4) = v;
            }
        }
        bK0 = bK1;           // placate c==63 path (values unused there)
        if (c < 63) { bK0 = nK0; bK1 = nK1; }
    }

    // ---- epilogue: cross-wave (n-half) O reduce, 2 passes of 32 m-cols ----
    const float gm = gammap[0];
    float* Olds = (float*)(void*)smem;   // [256][36] f32 = 36864 B, reuses Vlds
    #pragma unroll 1
    for (int p = 0; p < 2; ++p) {
        __syncthreads();
        if (h == 0 && (g >> 1) == p) {
            #pragma unroll
            for (int ot = 0; ot < 16; ++ot)
                #pragma unroll
                for (int r = 0; r < 4; ++r)
                    Olds[(ot * 16 + li) * 36 + (g & 1) * 16 + quad * 4 + r] = oacc[ot][r];
        }
        __syncthreads();
        if (h == 1 && (g >> 1) == p) {
            #pragma unroll
            for (int ot = 0; ot < 16; ++ot)
                #pragma unroll
                for (int r = 0; r < 4; ++r)
                    Olds[(ot * 16 + li) * 36 + (g & 1) * 16 + quad * 4 + r] += oacc[ot][r];
        }
        __syncthreads();
        #pragma unroll
        for (int it = 0; it < 4; ++it) {
            int linear = it * 512 + tid;
            int o = linear >> 3, seg = linear & 7;
            floatx4 ov = *(const floatx4*)(Olds + o * 36 + seg * 4);
            size_t gidx = (size_t)(b * OD + o) * NN + mw + p * 32 + seg * 4;
            floatx4 xv = *(const floatx4*)(x + gidx);
            floatx4 res;
            res[0] = gm * ov[0] + xv[0];
            res[1] = gm * ov[1] + xv[1];
            res[2] = gm * ov[2] + xv[2];
            res[3] = gm * ov[3] + xv[3];
            *(floatx4*)(out + gidx) = res;
        }
    }
}

extern "C" void kernel_launch(void* const* d_in, const int* in_sizes, int n_in,
                              void* d_out, int out_size, void* d_ws, size_t ws_size,
                              hipStream_t stream) {
    const float* x     = (const float*)d_in[0];
    const float* Wq    = (const float*)d_in[1];
    const float* bq    = (const float*)d_in[2];
    const float* Wk    = (const float*)d_in[3];
    const float* bk    = (const float*)d_in[4];
    const float* Wv    = (const float*)d_in[5];
    const float* bv    = (const float*)d_in[6];
    const float* gamma = (const float*)d_in[7];

    float* out  = (float*)d_out;
    float* attn = out + (size_t)NB * OD * NN;          // outputs concatenated: out then attention

    unsigned short* Qb  = (unsigned short*)d_ws;       // B*N*32 bf16 = 1 MB
    unsigned short* Ktb = Qb  + (size_t)NB * NN * KD;  // 1 MB
    unsigned short* Vb  = Ktb + (size_t)NB * NN * KD;  // B*O*N bf16 = 8 MB

    proj_kernel<<<dim3(640), 256, 0, stream>>>(x, Wq, bq, Wk, bk, Wv, bv, Qb, Ktb, Vb);
    attn_kernel<<<dim3(256), 512, 0, stream>>>(x, gamma, Qb, Ktb, Vb, out, attn);
}